// Round 5
// baseline (2582.657 us; speedup 1.0000x reference)
//
#include <hip/hip_runtime.h>
#include <hip/hip_bf16.h>

// ---------------------------------------------------------------------------
// MLXAttention on MI355X — fp32-accurate via fp16 hi/lo split GEMMs.
//
//   1. split x -> A2x [8192 x 8192] fp16 (cols 0..4095 hi, 4096.. lo);
//      split Wq/Wk/Wv/Wo likewise.
//   2. q = A2x (*) B2q + bq ; kv = A2x (*) [B2k;B2v] + [bk;bv]  (fused N=2048)
//      3-product MFMA GEMM (hi*hi + hi*lo + lo*hi), 256x256 tile, 8 waves,
//      v_mfma_f32_32x32x16_f16, 2 sync-points/K-step, counted-vmcnt dbuf.
//   3. per-token attention (softmax over 8 kv heads == reference's 32-way
//      over x4-tiled duplicates) -> split fp16 into A2x (reused).
//   4. out = A2attn (*) B2o + bo.
//
// K-step (BK=32), dbuf CUR/NXT, stage groups: G1={Ahi(2),Bhi(2)}, G23={Blo(2),Alo(2)}:
//   S1: vmcnt(4) bar | ds_read ah(8),bh(4) | issue G1'(4) | prio1 16 MFMA hh
//   S2: vmcnt(4) bar | ds_read bl(4) | issue G23'(4) | prio1 16 MFMA hl
//       | ds_read al(8) (overlaps hl) | prio1 16 MFMA lh
// Steady state 8 loads outstanding; own vmcnt(4) before each barrier makes the
// group's DMA visible to all waves. Never vmcnt(0) in-loop (T4).
// LDS swizzle (0 conflicts @16x16, re-derived conflict-free for 32x32 reads):
// stored unit(row,c16) = (row>>4)*64 + (row&15)*4 + (c16 ^ ((row>>1)&3));
// achieved by pre-swizzled global source col (linear gload_lds dest, rule 21).
// 32x32x16 operand: row = lane&31, k = (lane>>5)*8 + e  (extrapolated from
// verified 16x16 rule); C/D: col=lane&31, row=(reg&3)+8*(reg>>2)+4*(lane>>5)
// (HW-verified m74/m101).
//
// ws layout (bytes):            offset        size
//   A2x / A2attn (fp16)         0             134,217,728
//   B2q (fp16)                  134,217,728    67,108,864
//   B2k|B2v (fp16, contiguous)  201,326,592    33,554,432
//   B2o (fp16)                  234,881,024    67,108,864
//   q (f32)                     301,989,888   134,217,728
//   kv (f32) [8192][2048]       436,207,616    67,108,864
//   total                       503,316,480  (~480 MiB)
// ---------------------------------------------------------------------------

typedef _Float16 half8 __attribute__((ext_vector_type(8)));
typedef _Float16 half4v __attribute__((ext_vector_type(4)));
typedef float floatx16 __attribute__((ext_vector_type(16)));

#define K_DIM 4096
#define LDAB 8192   // row stride (halfs) of split matrices
#define BM 256
#define BN 256
#define BK 32
#define NSTEP 128   // K_DIM / BK

__device__ __forceinline__ void gload16(const void* g, void* l) {
    __builtin_amdgcn_global_load_lds((const __attribute__((address_space(1))) void*)g,
                                     (__attribute__((address_space(3))) void*)l,
                                     16, 0, 0);
}

// ---------------------------------------------------------------------------
__global__ __launch_bounds__(256) void split_f32(
    const float* __restrict__ src, _Float16* __restrict__ dst, long long rows) {
    long long n4 = rows * 1024;   // float4 count (4096 cols / 4)
    long long stride = (long long)gridDim.x * blockDim.x;
    for (long long i = (long long)blockIdx.x * blockDim.x + threadIdx.x; i < n4; i += stride) {
        float4 v = ((const float4*)src)[i];
        long long r = i >> 10;
        int c = ((int)(i & 1023)) << 2;
        half4v hi, lo;
        hi[0] = (_Float16)v.x; lo[0] = (_Float16)(v.x - (float)hi[0]);
        hi[1] = (_Float16)v.y; lo[1] = (_Float16)(v.y - (float)hi[1]);
        hi[2] = (_Float16)v.z; lo[2] = (_Float16)(v.z - (float)hi[2]);
        hi[3] = (_Float16)v.w; lo[3] = (_Float16)(v.w - (float)hi[3]);
        *(half4v*)&dst[r * LDAB + c] = hi;
        *(half4v*)&dst[r * LDAB + K_DIM + c] = lo;
    }
}

// ---------------------------------------------------------------------------
// C[M,N] = A2 (*) B2^T + bias, fused 3-product, 32x32x16 MFMA.
// 1-D grid, nwg % 8 == 0.  bias1 != nullptr => cols >= 1024 use bias1[col-1024].
// ---------------------------------------------------------------------------
__global__ __launch_bounds__(512, 2) void gemm_split3_8w(
    const _Float16* __restrict__ A, const _Float16* __restrict__ B,
    float* __restrict__ C, const float* __restrict__ bias0,
    const float* __restrict__ bias1, int N) {

    __shared__ __attribute__((aligned(16))) _Float16 lA[2][2][BM * BK];
    __shared__ __attribute__((aligned(16))) _Float16 lB[2][2][BN * BK];

    const int tid = threadIdx.x;
    const int lane = tid & 63;
    const int w = tid >> 6;          // wave 0..7
    const int wm = w >> 2;           // 0..1 -> 128-row half
    const int wn = w & 3;            // 0..3 -> 64-col quarter

    // chunked XCD swizzle + brow-major-within-bcol panel order
    const int f = blockIdx.x;
    const int nwg = gridDim.x;
    const int lid = (f & 7) * (nwg >> 3) + (f >> 3);
    const long long brow = (long long)(lid & 31) * BM;   // M/BM == 32 always
    const long long bcol = (long long)(lid >> 5) * BN;

    floatx16 acc[4][2];
#pragma unroll
    for (int m = 0; m < 4; ++m)
#pragma unroll
        for (int n = 0; n < 2; ++n)
            acc[m][n] = (floatx16)(0.f);

    // staging: issue covers rows i*128 + w*16 + (lane>>2); swizzled src col
    const int srow = w * 16 + (lane >> 2);
    const int scol = 8 * ((lane & 3) ^ ((lane >> 3) & 3));
    const _Float16* Asrc = A + (brow + srow) * (long long)LDAB + scol;
    const _Float16* Bsrc = B + (bcol + srow) * (long long)LDAB + scol;

    // 32x32 fragment read addressing (halfs), swizzle-matched:
    const int rl = lane & 31;
    const int rbase8 = ((rl >> 4) * 64 + (rl & 15) * 4) * 8;
    const int x0 = (((lane >> 5) ^ ((lane >> 1) & 3))) * 8;       // khalf 0
    const int x1 = (((2 + (lane >> 5)) ^ ((lane >> 1) & 3))) * 8; // khalf 1

    auto stageG1 = [&](int NXT, int ktn) {   // Ahi + Bhi (4 loads)
        gload16(Asrc + ktn, &lA[NXT][0][w * 512]);
        gload16(Asrc + 128 * (long long)LDAB + ktn, &lA[NXT][0][4096 + w * 512]);
        gload16(Bsrc + ktn, &lB[NXT][0][w * 512]);
        gload16(Bsrc + 128 * (long long)LDAB + ktn, &lB[NXT][0][4096 + w * 512]);
    };
    auto stageG23 = [&](int NXT, int ktn) {  // Blo + Alo (4 loads)
        gload16(Bsrc + K_DIM + ktn, &lB[NXT][1][w * 512]);
        gload16(Bsrc + 128 * (long long)LDAB + K_DIM + ktn, &lB[NXT][1][4096 + w * 512]);
        gload16(Asrc + K_DIM + ktn, &lA[NXT][1][w * 512]);
        gload16(Asrc + 128 * (long long)LDAB + K_DIM + ktn, &lA[NXT][1][4096 + w * 512]);
    };

    // prologue: fill buffer 0 (8 outstanding, no drain)
    stageG1(0, 0);
    stageG23(0, 0);

    auto step = [&](int CUR, int NXT, int ktn) {
        half8 ah[4][2], bh[2][2];
        // ---- S1: need G1(CUR) = oldest 4 of 8 outstanding ----
        asm volatile("s_waitcnt vmcnt(4)" ::: "memory");
        __builtin_amdgcn_s_barrier();
#pragma unroll
        for (int nf = 0; nf < 2; ++nf) {
            bh[nf][0] = *(const half8*)&lB[CUR][0][(wn * 4 + nf * 2) * 512 + rbase8 + x0];
            bh[nf][1] = *(const half8*)&lB[CUR][0][(wn * 4 + nf * 2) * 512 + rbase8 + x1];
        }
#pragma unroll
        for (int mf = 0; mf < 4; ++mf) {
            ah[mf][0] = *(const half8*)&lA[CUR][0][(wm * 8 + mf * 2) * 512 + rbase8 + x0];
            ah[mf][1] = *(const half8*)&lA[CUR][0][(wm * 8 + mf * 2) * 512 + rbase8 + x1];
        }
        stageG1(NXT, ktn);
        __builtin_amdgcn_s_setprio(1);
#pragma unroll
        for (int mf = 0; mf < 4; ++mf)
#pragma unroll
            for (int nf = 0; nf < 2; ++nf) {
                acc[mf][nf] = __builtin_amdgcn_mfma_f32_32x32x16_f16(
                    ah[mf][0], bh[nf][0], acc[mf][nf], 0, 0, 0);
                acc[mf][nf] = __builtin_amdgcn_mfma_f32_32x32x16_f16(
                    ah[mf][1], bh[nf][1], acc[mf][nf], 0, 0, 0);
            }
        __builtin_amdgcn_s_setprio(0);
        // ---- S2: need G23(CUR); after vmcnt(4) only G1'(4) outstanding ----
        asm volatile("s_waitcnt vmcnt(4)" ::: "memory");
        __builtin_amdgcn_s_barrier();
        {
            half8 bl[2][2];
#pragma unroll
            for (int nf = 0; nf < 2; ++nf) {
                bl[nf][0] = *(const half8*)&lB[CUR][1][(wn * 4 + nf * 2) * 512 + rbase8 + x0];
                bl[nf][1] = *(const half8*)&lB[CUR][1][(wn * 4 + nf * 2) * 512 + rbase8 + x1];
            }
            stageG23(NXT, ktn);
            __builtin_amdgcn_s_setprio(1);
#pragma unroll
            for (int mf = 0; mf < 4; ++mf)
#pragma unroll
                for (int nf = 0; nf < 2; ++nf) {
                    acc[mf][nf] = __builtin_amdgcn_mfma_f32_32x32x16_f16(
                        ah[mf][0], bl[nf][0], acc[mf][nf], 0, 0, 0);
                    acc[mf][nf] = __builtin_amdgcn_mfma_f32_32x32x16_f16(
                        ah[mf][1], bl[nf][1], acc[mf][nf], 0, 0, 0);
                }
            __builtin_amdgcn_s_setprio(0);
        }
        {
            half8 al[4][2];   // ah dead after hl -> regs recycle
#pragma unroll
            for (int mf = 0; mf < 4; ++mf) {
                al[mf][0] = *(const half8*)&lA[CUR][1][(wm * 8 + mf * 2) * 512 + rbase8 + x0];
                al[mf][1] = *(const half8*)&lA[CUR][1][(wm * 8 + mf * 2) * 512 + rbase8 + x1];
            }
            __builtin_amdgcn_s_setprio(1);
#pragma unroll
            for (int mf = 0; mf < 4; ++mf)
#pragma unroll
                for (int nf = 0; nf < 2; ++nf) {
                    acc[mf][nf] = __builtin_amdgcn_mfma_f32_32x32x16_f16(
                        al[mf][0], bh[nf][0], acc[mf][nf], 0, 0, 0);
                    acc[mf][nf] = __builtin_amdgcn_mfma_f32_32x32x16_f16(
                        al[mf][1], bh[nf][1], acc[mf][nf], 0, 0, 0);
                }
            __builtin_amdgcn_s_setprio(0);
        }
    };

    for (int tt = 0; tt < NSTEP; tt += 2) {
        step(0, 1, (tt + 1) * BK);
        step(1, 0, ((tt + 2) & (NSTEP - 1)) * BK);   // wrap: harmless in-bounds prefetch
    }
    asm volatile("s_waitcnt vmcnt(0)" ::: "memory");  // drain leftovers (once)

    // epilogue: C/D 32x32 layout col=lane&31, row=(reg&3)+8*(reg>>2)+4*(lane>>5)
    const float* bias = (bias1 != nullptr && bcol >= 1024) ? (bias1 - 1024) : bias0;
    const int r0 = 4 * (lane >> 5);
#pragma unroll
    for (int nf = 0; nf < 2; ++nf) {
        long long col = bcol + wn * 64 + nf * 32 + rl;
        float bv_ = bias[col];
#pragma unroll
        for (int mf = 0; mf < 4; ++mf) {
            long long rowb = brow + wm * 128 + mf * 32 + r0;
#pragma unroll
            for (int g = 0; g < 4; ++g)
#pragma unroll
                for (int rr = 0; rr < 4; ++rr) {
                    long long row = rowb + 8 * g + rr;
                    __builtin_nontemporal_store(acc[mf][nf][g * 4 + rr] + bv_,
                                                C + row * (long long)N + col);
                }
        }
    }
}

// ---------------------------------------------------------------------------
// Per-token attention. Reference tiles k/v x4 over heads then softmaxes over
// 32 scores; duplicated columns reduce exactly to softmax over 8 kv heads.
// kv: [8192][2048] f32, cols 0..1023 = K (8 heads x 128), 1024.. = V.
// ---------------------------------------------------------------------------
__global__ __launch_bounds__(256) void attn_token(
    const float* __restrict__ q, const float* __restrict__ kv,
    _Float16* __restrict__ out) {

    const int token = blockIdx.x;
    __shared__ float sQ[32 * 128];
    __shared__ float sK[8 * 128];
    __shared__ float sV[8 * 128];
    __shared__ float sP[32 * 8];

    const int t = threadIdx.x;
    {
        const float4* gq = (const float4*)(q + (long long)token * 4096);
        float4* dq = (float4*)sQ;
        dq[t] = gq[t];
        dq[t + 256] = gq[t + 256];
        dq[t + 512] = gq[t + 512];
        dq[t + 768] = gq[t + 768];
        const float4* gkv = (const float4*)(kv + (long long)token * 2048);
        ((float4*)sK)[t] = gkv[t];
        ((float4*)sV)[t] = gkv[t + 256];
    }
    __syncthreads();

    const int h = t >> 3, j = t & 7;
    const float* qr = sQ + h * 128;
    const float* kr = sK + j * 128;
    float s = 0.f;
#pragma unroll
    for (int i = 0; i < 128; i += 4)
        s += qr[i] * kr[i] + qr[i + 1] * kr[i + 1] +
             qr[i + 2] * kr[i + 2] + qr[i + 3] * kr[i + 3];
    s *= 0.08838834764831845f;   // 1/sqrt(128)

    float mx = s;
    mx = fmaxf(mx, __shfl_xor(mx, 1, 8));
    mx = fmaxf(mx, __shfl_xor(mx, 2, 8));
    mx = fmaxf(mx, __shfl_xor(mx, 4, 8));
    float e = expf(s - mx);
    float sum = e;
    sum += __shfl_xor(sum, 1, 8);
    sum += __shfl_xor(sum, 2, 8);
    sum += __shfl_xor(sum, 4, 8);
    sP[t] = e / sum;
    __syncthreads();

    float p[8];
#pragma unroll
    for (int jj = 0; jj < 8; ++jj) p[jj] = sP[(t >> 3) * 8 + jj];
    const int d0 = (t & 7) * 16;
    const long long obase = (long long)token * LDAB + (t >> 3) * 128;
#pragma unroll
    for (int dd = 0; dd < 16; ++dd) {
        int d = d0 + dd;
        float a = 0.f;
#pragma unroll
        for (int jj = 0; jj < 8; ++jj) a += p[jj] * sV[jj * 128 + d];
        _Float16 hi = (_Float16)a;
        _Float16 lo = (_Float16)(a - (float)hi);
        out[obase + d] = hi;
        out[obase + K_DIM + d] = lo;
    }
}

// ---------------------------------------------------------------------------
extern "C" void kernel_launch(void* const* d_in, const int* in_sizes, int n_in,
                              void* d_out, int out_size, void* d_ws, size_t ws_size,
                              hipStream_t stream) {
    const float* x  = (const float*)d_in[0];
    const float* Wq = (const float*)d_in[1];
    const float* bq = (const float*)d_in[2];
    const float* Wk = (const float*)d_in[3];
    const float* bk = (const float*)d_in[4];
    const float* Wv = (const float*)d_in[5];
    const float* bv = (const float*)d_in[6];
    const float* Wo = (const float*)d_in[7];
    const float* bo = (const float*)d_in[8];
    float* out = (float*)d_out;

    char* ws = (char*)d_ws;
    _Float16* A2x  = (_Float16*)(ws + 0);            // reused for attn output
    _Float16* B2q  = (_Float16*)(ws + 134217728LL);
    _Float16* B2kv = (_Float16*)(ws + 201326592LL);  // B2k then B2v, contiguous
    _Float16* B2v  = (_Float16*)(ws + 218103808LL);
    _Float16* B2o  = (_Float16*)(ws + 234881024LL);
    float*    qb   = (float*)(ws + 301989888LL);
    float*    kvb  = (float*)(ws + 436207616LL);     // [8192][2048]

    // 1. splits (fp32 -> hi/lo fp16)
    split_f32<<<2048, 256, 0, stream>>>(x,  A2x, 8192);
    split_f32<<<2048, 256, 0, stream>>>(Wq, B2q, 4096);
    split_f32<<<1024, 256, 0, stream>>>(Wk, B2kv, 1024);
    split_f32<<<1024, 256, 0, stream>>>(Wv, B2v, 1024);
    split_f32<<<2048, 256, 0, stream>>>(Wo, B2o, 4096);

    // 2. projections
    gemm_split3_8w<<<512, 512, 0, stream>>>(A2x, B2q,  qb,  bq, nullptr, 4096);
    gemm_split3_8w<<<256, 512, 0, stream>>>(A2x, B2kv, kvb, bk, bv,      2048);

    // 3. per-token attention -> split fp16 into A2x
    attn_token<<<8192, 256, 0, stream>>>(qb, kvb, A2x);

    // 4. output projection
    gemm_split3_8w<<<512, 512, 0, stream>>>(A2x, B2o, out, bo, nullptr, 4096);
}